// Round 15
// baseline (377.564 us; speedup 1.0000x reference)
//
#include <hip/hip_runtime.h>

// Problem constants
#define BB        16
#define HH        6
#define WW        4096
#define CC        128
#define TT        1024          // W/OVERLAP
#define NTOK      16384         // B*T
#define FIX       768           // H*C
#define HID       1024
#define CBK       1024
#define CBD       8
#define NPVQ      3
#define NRVQ      6
#define ZQ_SIZE   50331648ull   // B*H*W*C

// ws layout (byte offsets), all 16-aligned
#define OFF_ACC   0ull                            // 16 B loss accumulator (double)
#define OFF_EN64  16ull                           // 18*1024*8 f64 = 1179648 B
#define OFF_EN32  (OFF_EN64 + 1179648ull)         // 18*1024*8 f32 = 589824 B
#define OFF_PUT   (OFF_EN32 + 589824ull)          // 3*1024*8 f32  = 98304 B
#define OFF_R     (OFF_PUT + 98304ull)            // 3*16384*8 f64 = 3145728 B
#define OFF_ZQ    (OFF_R + 3145728ull)            // 3*16384*8 f32 = 1572864 B

typedef float v2f __attribute__((ext_vector_type(2)));

// ---------------------------------------------------------------------------
// Kernel A (merged): blocks [0,72) l2-normalize codebooks -> en64 + en32;
// blocks [72,168) transpose pu -> pu_t. One launch instead of two.
// ---------------------------------------------------------------------------
__global__ __launch_bounds__(256) void kprep(const float* __restrict__ emb,
                                             double* __restrict__ en64,
                                             float* __restrict__ en32,
                                             const float* __restrict__ pu,
                                             float* __restrict__ pu_t) {
    const int bid = blockIdx.x;
    if (bid < 72) {
        int gid = bid * 256 + threadIdx.x;
        if (gid >= NPVQ * NRVQ * CBK) return;
        const float* e = emb + (size_t)gid * CBD;
        double v[CBD];
        double s = 0.0;
#pragma unroll
        for (int d = 0; d < CBD; ++d) { v[d] = (double)e[d]; s += v[d] * v[d]; }
        double n = fmax(sqrt(s), 1e-12);
#pragma unroll
        for (int d = 0; d < CBD; ++d) {
            double q = v[d] / n;
            en64[(size_t)gid * CBD + d] = q;
            en32[(size_t)gid * CBD + d] = (float)q;
        }
    } else {
        int gid = (bid - 72) * 256 + threadIdx.x;
        if (gid >= NPVQ * CBD * HID) return;
        int j = gid & (HID - 1), md = gid >> 10;
        int m = md >> 3, d = md & 7;
        pu_t[((size_t)m * HID + j) * CBD + d] = pu[gid];
    }
}

// ---------------------------------------------------------------------------
// Kernel B: gather 2 tokens (24 KB) into LDS, project 1024->8 (fp64).
// 384 thr = 6 waves: wave w -> token (w>=3), m = w%3. (R5 index fix kept;
// coalesced contiguous-line reads + LDS scatter — R14 showed the per-lane
// direct gather is a 16x over-fetch, so this stays a separate kernel.)
// ---------------------------------------------------------------------------
__global__ __launch_bounds__(384) void kproj(const float* __restrict__ ze,
                                             const float* __restrict__ pd,
                                             double* __restrict__ r_ws) {
    __shared__ float x[2][NPVQ * HID];   // 24 KB
    const int tok0 = blockIdx.x * 2;
    const int b = tok0 >> 10, t0 = tok0 & 1023;
    const int tid = threadIdx.x;
    const size_t zbase = (size_t)b * (HH * WW * CC);
#pragma unroll
    for (int q = 0; q < 4; ++q) {
        int g = tid + 384 * q;                 // [0,1536)
        int tk = g >= 768;
        int gg = g - tk * 768;                 // (768 not pow2 — no masking!)
        int h = gg >> 7, v = gg & 127;
        const float4 val = *(const float4*)(ze + zbase + (size_t)(h * WW + (t0 + tk) * 4) * CC + v * 4);
        float vv[4] = {val.x, val.y, val.z, val.w};
#pragma unroll
        for (int e = 0; e < 4; ++e) {
            int oc = v * 4 + e, o = oc >> 7, c = oc & 127;
            x[tk][o * FIX + c * HH + h] = vv[e];
        }
    }
    __syncthreads();
    const int w = tid >> 6, l = tid & 63;
    const int tk = w >= 3, m = w - tk * 3;
    double acc[CBD] = {0, 0, 0, 0, 0, 0, 0, 0};
    for (int q = 0; q < 16; ++q) {
        int j = l + 64 * q;
        double xv = (double)x[tk][m * HID + j];
        const float* pr = pd + (size_t)(m * HID + j) * CBD;
#pragma unroll
        for (int d = 0; d < CBD; ++d) acc[d] = fma(xv, (double)pr[d], acc[d]);
    }
#pragma unroll
    for (int off = 32; off >= 1; off >>= 1) {
#pragma unroll
        for (int d = 0; d < CBD; ++d) acc[d] += __shfl_down(acc[d], off, 64);
    }
    if (l == 0) {
        double* rp = r_ws + ((size_t)m * NTOK + tok0 + tk) * CBD;
#pragma unroll
        for (int d = 0; d < CBD; ++d) rp[d] = acc[d];
    }
}

// ---------------------------------------------------------------------------
// Kernel C: residual VQ. fp32 certified scan + targeted fp64 recert.
// R15: SGPR-TILE SCAN. Insight from R8..R14: any path that broadcasts a code
// into VGPRs pays a 64-lane x 16 B register-file fanout per instruction
// (~12-16 cy) — that fanout IS the 184 us wall (LDS b128 and VMEM dwordx4
// both hit it). Codes are wave-uniform, so load them into SGPRs instead
// (64 B once, no fanout): readfirstlane makes the slice base provably
// uniform -> compiler emits batched s_load tiles -> dots via
// v_fmac_f32(vdst, sgpr, vgpr). 4-code tiles (32 SGPRs), one wait per tile,
// ~200 cy L2 latency hidden by 6 waves/SIMD x ~90 cy compute per tile.
// No LDS table, no staging, no staging barriers (LDS = 12.5 KB merge only).
// Scalar fmaf chains a0/a1 == the packed lo/hi chains (same op order) ->
// dots bit-identical to R7/R8 -> decisions unchanged.
// ---------------------------------------------------------------------------
#define KV_WAVES    8
#define KV_THREADS  (KV_WAVES * 64)
#define KV_WSLICE   (CBK / KV_WAVES)   // 128
#define KV_TILE     4                  // codes per SGPR tile
#define KV_EPS      2e-6f              // cert gap  (> 2x fp32 8-dot err bound)
#define KV_EPS_CAND 2e-6f              // candidate window (same 2e bound)

__global__ __launch_bounds__(KV_THREADS, 2) void kvq(const double* __restrict__ en_all,
                                                     const float* __restrict__ es_all,
                                                     const double* __restrict__ r_ws,
                                                     float* __restrict__ zq_ws,
                                                     float* __restrict__ out,   // d_out base
                                                     const int* __restrict__ nsp,
                                                     double* __restrict__ accum) {
    __shared__ float  mb1[KV_THREADS];               // 2 KB
    __shared__ float  mb2[KV_THREADS];               // 2 KB
    __shared__ int    mbk[KV_THREADS];               // 2 KB
    __shared__ double md64[KV_THREADS];              // 4 KB (recert merge)
    __shared__ int    mk64[KV_THREADS];              // 2 KB

    const int blk = blockIdx.x;
    const int m = blk >> 8, g = blk & 255;
    const int tid = threadIdx.x;
    const int w = tid >> 6, l = tid & 63;
    const int tok = g * 64 + l;
    const int b = tok >> 10, t = tok & 1023;
    const int ns = *nsp;

    double r[CBD];
    {
        const double* rp = r_ws + ((size_t)m * NTOK + tok) * CBD;
#pragma unroll
        for (int d = 0; d < CBD; ++d) r[d] = rp[d];
    }
    float zq[CBD];
#pragma unroll
    for (int d = 0; d < CBD; ++d) zq[d] = 0.0f;
    double loss = 0.0;

    // wave-uniform slice base, provably scalar for the compiler
    const int k0s = __builtin_amdgcn_readfirstlane(w * KV_WSLICE);

    for (int i = 0; i < ns; ++i) {
        const double* en = en_all + ((size_t)(m * NRVQ + i)) * CBK * CBD;
        const float*  es = es_all + ((size_t)(m * NRVQ + i)) * CBK * CBD;
        // rn = fp64-normalized residual, cast fp32 (scan is scale-invariant)
        double s = 0.0;
#pragma unroll
        for (int d = 0; d < CBD; ++d) s += r[d] * r[d];
        double inv = 1.0 / fmax(sqrt(s), 1e-12);
        float rn[CBD];
#pragma unroll
        for (int d = 0; d < CBD; ++d) rn[d] = (float)(r[d] * inv);

        float b1 = -1e30f, b2 = -1e30f;
        int bk = k0s;
        for (int kt = 0; kt < KV_WSLICE; kt += KV_TILE) {
            const int kb = k0s + kt;           // SGPR arithmetic
            float ek[KV_TILE][CBD];            // uniform -> s_load tile, SGPRs
#pragma unroll
            for (int c = 0; c < KV_TILE; ++c)
#pragma unroll
                for (int d = 0; d < CBD; ++d)
                    ek[c][d] = es[(size_t)(kb + c) * CBD + d];
#pragma unroll
            for (int c = 0; c < KV_TILE; ++c) {
                // a0/a1 split chains — same op order as the packed dot ->
                // bit-identical values
                float a0 = 0.0f, a1 = 0.0f;
#pragma unroll
                for (int d = 0; d < CBD; d += 2) {
                    a0 = fmaf(rn[d], ek[c][d], a0);
                    a1 = fmaf(rn[d + 1], ek[c][d + 1], a1);
                }
                float dv = a0 + a1;
                if (dv > b1) { b2 = b1; b1 = dv; bk = kb + c; }  // strict >: first max
                else if (dv > b2) { b2 = dv; }
            }
        }
        __syncthreads();   // merge arrays free (prev stream's readers done)
        mb1[tid] = b1; mb2[tid] = b2; mbk[tid] = bk;
        __syncthreads();
        // 8-way top-2 merge (slices ascending in w -> strict > keeps first max)
        float B1 = mb1[l], B2 = mb2[l];
        int K = mbk[l];
#pragma unroll
        for (int w2 = 1; w2 < KV_WAVES; ++w2) {
            float c1 = mb1[w2 * 64 + l];
            float c2 = mb2[w2 * 64 + l];
            int   ck = mbk[w2 * 64 + l];
            if (c1 > B1) { B2 = fmaxf(B1, c2); B1 = c1; K = ck; }
            else         { B2 = fmaxf(B2, c1); }
        }
        int bbk = K;
        // certification: fp32 gap > EPS  =>  fp32 winner == fp64 argmax.
        // unc identical in every wave => __any block-uniform => safe barriers.
        bool uncert = (B1 - B2) <= KV_EPS;
        if (__any(uncert)) {
            __syncthreads();   // all waves done reading the merge arrays
            double rb = -1e300;
            int rk = CBK;      // sentinel (larger than any real index)
            for (int kt = 0; kt < KV_WSLICE; kt += KV_TILE) {
                const int kb = k0s + kt;
                float ek[KV_TILE][CBD];
#pragma unroll
                for (int c = 0; c < KV_TILE; ++c)
#pragma unroll
                    for (int d = 0; d < CBD; ++d)
                        ek[c][d] = es[(size_t)(kb + c) * CBD + d];
#pragma unroll
                for (int c = 0; c < KV_TILE; ++c) {
                    float a0 = 0.0f, a1 = 0.0f;
#pragma unroll
                    for (int d = 0; d < CBD; d += 2) {
                        a0 = fmaf(rn[d], ek[c][d], a0);
                        a1 = fmaf(rn[d + 1], ek[c][d + 1], a1);
                    }
                    float dv = a0 + a1;            // identical recompute
                    bool cand = uncert && (dv >= B1 - KV_EPS_CAND);
                    if (__any(cand)) {
                        // uniform-address fp64 code load (scalar path, rare)
                        double e64[CBD];
#pragma unroll
                        for (int d = 0; d < CBD; ++d) e64[d] = en[(size_t)(kb + c) * CBD + d];
                        double q0 = 0.0, q1 = 0.0;
#pragma unroll
                        for (int d = 0; d < CBD; d += 2) {
                            q0 = fma(r[d], e64[d], q0);
                            q1 = fma(r[d + 1], e64[d + 1], q1);
                        }
                        double dot = q0 + q1;
                        if (cand && (dot > rb || (dot == rb && (kb + c) < rk))) {
                            rb = dot; rk = kb + c;
                        }
                    }
                }
            }
            md64[tid] = rb; mk64[tid] = rk;
            __syncthreads();
            if (uncert) {
                double R = md64[l];
                int RK = mk64[l];
#pragma unroll
                for (int w2 = 1; w2 < KV_WAVES; ++w2) {
                    double d2 = md64[w2 * 64 + l];
                    int    k2 = mk64[w2 * 64 + l];
                    if (d2 > R || (d2 == R && k2 < RK)) { R = d2; RK = k2; }
                }
                bbk = RK;
            }
        }
        // winner vector in fp64 (L2-resident), exact residual/loss updates
        const double* qv = en + (size_t)bbk * CBD;
        if (w == 0) {
            double ls = 0.0;
#pragma unroll
            for (int d = 0; d < CBD; ++d) { double df = qv[d] - r[d]; ls += df * df; }
            loss += ls;
            out[ZQ_SIZE + ((size_t)(b * ns + i) * NPVQ + m) * TT + t] = (float)bbk;
        }
#pragma unroll
        for (int d = 0; d < CBD; ++d) {
            double q = qv[d];
            r[d] -= q;
            zq[d] += (float)q;
        }
    }

    if (w == 0) {
        float* zp = zq_ws + ((size_t)m * NTOK + tok) * CBD;
#pragma unroll
        for (int d = 0; d < CBD; ++d) zp[d] = zq[d];
#pragma unroll
        for (int off = 32; off >= 1; off >>= 1) loss += __shfl_down(loss, off, 64);
        if (l == 0) atomicAdd(accum, loss);
    }
}

// ---------------------------------------------------------------------------
// Kernel D: up-projection 8->1024 + inverse permutation scatter (coalesced),
// plus loss epilogue. Block = 32 consecutive tokens. Packed v_pk_fma_f32
// epilogue (post-decision fp32; order change harmless). Proven in R13/R14.
// ---------------------------------------------------------------------------
__global__ __launch_bounds__(256) void kout(const float* __restrict__ pu_t,
                                            const float* __restrict__ zq_ws,
                                            float* __restrict__ out,
                                            const int* __restrict__ nsp,
                                            const double* __restrict__ accum) {
    __shared__ float zl[32][NPVQ][CBD];   // 3 KB
    const int blk = blockIdx.x;
    const int tok0 = blk * 32;
    const int b = tok0 >> 10, t0 = tok0 & 1023;
    const int tid = threadIdx.x;
#pragma unroll
    for (int q = 0; q < 3; ++q) {
        int ii = tid + 256 * q;            // [0,768)
        int mm = ii >> 8, rem = ii & 255, tt = rem >> 3, d = rem & 7;
        zl[tt][mm][d] = zq_ws[((size_t)mm * NTOK + tok0 + tt) * CBD + d];
    }
    __syncthreads();
    const size_t obase = (size_t)b * (HH * WW * CC);
#pragma unroll 2
    for (int q = 0; q < 12; ++q) {
        int idx = tid + 256 * q;           // (h,o,c) linear
        int h = idx >> 9, rem = idx & 511, o = rem >> 7, c = rem & 127;
        int f = o * FIX + c * HH + h;
        int m = f >> 10, j = f & 1023;
        const float4* p4 = (const float4*)(pu_t + ((size_t)m * HID + j) * CBD);
        float4 pa = p4[0], pb = p4[1];
        v2f pw[4];
        pw[0].x = pa.x; pw[0].y = pa.y;
        pw[1].x = pa.z; pw[1].y = pa.w;
        pw[2].x = pb.x; pw[2].y = pb.y;
        pw[3].x = pb.z; pw[3].y = pb.w;
        size_t rowbase = obase + ((size_t)h * WW + t0 * 4 + o) * CC + c;
        for (int tt = 0; tt < 32; ++tt) {
            const float4* z4 = (const float4*)&zl[tt][m][0];
            float4 za = z4[0], zb = z4[1];
            v2f acc = {0.0f, 0.0f};
            v2f zz;
            zz.x = za.x; zz.y = za.y; acc = __builtin_elementwise_fma(zz, pw[0], acc);
            zz.x = za.z; zz.y = za.w; acc = __builtin_elementwise_fma(zz, pw[1], acc);
            zz.x = zb.x; zz.y = zb.y; acc = __builtin_elementwise_fma(zz, pw[2], acc);
            zz.x = zb.z; zz.y = zb.w; acc = __builtin_elementwise_fma(zz, pw[3], acc);
            out[rowbase + (size_t)tt * 4 * CC] = acc.x + acc.y;
        }
    }
    if (blk == 0 && tid == 0) {
        int ns = *nsp;
        double s = *accum;
        float lv = (float)(s / (double)(NTOK * CBD * NPVQ));
        size_t lbase = ZQ_SIZE + (size_t)BB * ns * NPVQ * TT;
        out[lbase] = lv;       // cb_loss / 3
        out[lbase + 1] = lv;   // cm_loss / 3 (numerically identical)
    }
}

// ---------------------------------------------------------------------------
extern "C" void kernel_launch(void* const* d_in, const int* in_sizes, int n_in,
                              void* d_out, int out_size, void* d_ws, size_t ws_size,
                              hipStream_t stream) {
    const float* ze  = (const float*)d_in[0];
    const float* emb = (const float*)d_in[1];
    const float* pd  = (const float*)d_in[2];
    const float* pu  = (const float*)d_in[3];
    const int*   nsp = (const int*)d_in[4];
    float* out = (float*)d_out;
    char* ws = (char*)d_ws;

    double* accum = (double*)(ws + OFF_ACC);
    double* en64  = (double*)(ws + OFF_EN64);
    float*  en32  = (float*)(ws + OFF_EN32);
    float*  pu_t  = (float*)(ws + OFF_PUT);
    double* r_ws  = (double*)(ws + OFF_R);
    float*  zq_ws = (float*)(ws + OFF_ZQ);

    hipMemsetAsync(accum, 0, 16, stream);
    kprep<<<168, 256, 0, stream>>>(emb, en64, en32, pu, pu_t);
    kproj<<<NTOK / 2, 384, 0, stream>>>(ze, pd, r_ws);
    kvq<<<NPVQ * (NTOK / 64), KV_THREADS, 0, stream>>>(en64, en32, r_ws, zq_ws, out, nsp, accum);
    kout<<<NTOK / 32, 256, 0, stream>>>(pu_t, zq_ws, out, nsp, accum);
}